// Round 2
// baseline (1081.677 us; speedup 1.0000x reference)
//
#include <hip/hip_runtime.h>
#include <cstddef>

#define EPSF 1e-12f

constexpr int Bc = 16, Dc = 128, Lc = 4096, Kc = 4096;
constexpr int Nc = Bc * Lc;   // 65536
constexpr float TAU = 2e-4f;  // repair margin (worst-case split err ~1e-5)
constexpr int RCAP = 8192;

typedef __attribute__((ext_vector_type(8))) short short8;
typedef __attribute__((ext_vector_type(4))) float f32x4;

// manual bf16 split (RNE) — rounding mode irrelevant for correctness, only err bound
__device__ __forceinline__ unsigned short f2bf(float f) {
    unsigned u = __float_as_uint(f);
    return (unsigned short)((u + 0x7fffu + ((u >> 16) & 1u)) >> 16);
}
__device__ __forceinline__ float bf2f(unsigned short u) {
    return __uint_as_float(((unsigned)u) << 16);
}

// ---------------------------------------------------------------------------
// Normalize codebook -> cbn (f32, for gather+repair) + cbh/cbl (bf16 split).
// One wave per row. Also zero-inits loss acc + repair count.
// ---------------------------------------------------------------------------
__global__ void k_cbprep(const float* __restrict__ emb, float* __restrict__ cbn,
                         unsigned short* __restrict__ cbh, unsigned short* __restrict__ cbl,
                         float* __restrict__ lacc, int* __restrict__ rcnt) {
    int k    = (blockIdx.x << 2) + (threadIdx.x >> 6);
    int lane = threadIdx.x & 63;
    float2 v = ((const float2*)(emb + (size_t)k * Dc))[lane];
    float s = v.x * v.x + v.y * v.y;
    #pragma unroll
    for (int off = 32; off > 0; off >>= 1) s += __shfl_down(s, off);
    s = __shfl(s, 0);
    float inv = 1.f / fmaxf(sqrtf(s), EPSF);
    v.x *= inv; v.y *= inv;
    ((float2*)(cbn + (size_t)k * Dc))[lane] = v;
    unsigned short h0 = f2bf(v.x), h1 = f2bf(v.y);
    ((unsigned int*)(cbh + (size_t)k * Dc))[lane] = (unsigned)h0 | ((unsigned)h1 << 16);
    unsigned short l0b = f2bf(v.x - bf2f(h0)), l1b = f2bf(v.y - bf2f(h1));
    ((unsigned int*)(cbl + (size_t)k * Dc))[lane] = (unsigned)l0b | ((unsigned)l1b << 16);
    if (blockIdx.x == 0 && threadIdx.x == 0) { *lacc = 0.f; *rcnt = 0; }
}

// ---------------------------------------------------------------------------
// MFMA argmax: 128 queries/block vs all 4096 codes via split-bf16 3-pass
// 16x16x32 MFMA (verified layouts). A (queries) in registers; B (codes)
// streamed 128/tile through 64KB XOR-swizzled LDS with register prefetch.
// Tracks (best, second, idx) per row; margin<TAU rows go to repair list.
// ---------------------------------------------------------------------------
__global__ __launch_bounds__(256, 1)
void k_argmax(const float* __restrict__ x, const unsigned short* __restrict__ cbh,
              const unsigned short* __restrict__ cbl, float* __restrict__ invn,
              int* __restrict__ idx_out, float* __restrict__ lossacc,
              int* __restrict__ rcnt, int* __restrict__ rlist) {
    __shared__ __align__(16) char smem[65536];
    float* xt   = (float*)smem;                 // [64][129] f32 (preamble)
    float* invl = (float*)(smem + 33024);       // [64] (preamble)
    unsigned short* bhp = (unsigned short*)smem;            // [128][128] bf16 hi (k-loop)
    unsigned short* blp = (unsigned short*)(smem + 32768);  // lo
    float* Ev = (float*)smem;                   // [64][32] (epilogue)
    float* Sv = (float*)(smem + 8192);
    int*   Kv = (int*)(smem + 16384);
    float* bsum = (float*)(smem + 24576);

    const int tid  = threadIdx.x;
    const int w    = tid >> 6;
    const int lane = tid & 63;
    const int m16  = lane & 15;
    const int quad = lane >> 4;
    const int n0   = blockIdx.x * 128;
    const int bIdx = n0 >> 12;
    const int l0   = n0 & (Lc - 1);
    const float* xb = x + (size_t)bIdx * Dc * Lc;

    short8 ah[4][4], al[4][4];   // [rowTile][kd] A fragments, hi/lo

    // ---- preamble: load/normalize/split x-tile, build A frags (2 halves) ----
    for (int h = 0; h < 2; ++h) {
        __syncthreads();
        #pragma unroll
        for (int j = 0; j < 8; ++j) {
            int fl = tid + j * 256;              // 0..2047
            int d = fl >> 4, lq = fl & 15;
            float4 v = *(const float4*)(xb + (size_t)d * Lc + l0 + h * 64 + lq * 4);
            xt[(lq * 4 + 0) * 129 + d] = v.x;
            xt[(lq * 4 + 1) * 129 + d] = v.y;
            xt[(lq * 4 + 2) * 129 + d] = v.z;
            xt[(lq * 4 + 3) * 129 + d] = v.w;
        }
        __syncthreads();
        {   // row norms (4 threads per row)
            int row = tid >> 2, q = tid & 3;
            float s = 0.f;
            #pragma unroll
            for (int j = 0; j < 32; ++j) { float t = xt[row * 129 + q * 32 + j]; s += t * t; }
            s += __shfl_down(s, 1); s += __shfl_down(s, 2);
            if (q == 0) {
                float inv = 1.f / fmaxf(sqrtf(s), EPSF);
                invl[row] = inv;
                invn[n0 + h * 64 + row] = inv;
            }
        }
        __syncthreads();
        if ((w >> 1) == h) {   // waves owning these 64 rows build their frags
            #pragma unroll
            for (int rt = 0; rt < 4; ++rt) {
                int rl = rt * 16 + m16;          // A layout: m = lane&15
                float inv = invl[rl];
                #pragma unroll
                for (int kd = 0; kd < 4; ++kd) {
                    int dof = kd * 32 + quad * 8;   // k = quad*8+j
                    short8 hh, ll;
                    #pragma unroll
                    for (int j = 0; j < 8; ++j) {
                        float xn = xt[rl * 129 + dof + j] * inv;
                        unsigned short hb = f2bf(xn);
                        hh[j] = (short)hb;
                        ll[j] = (short)f2bf(xn - bf2f(hb));
                    }
                    ah[rt][kd] = hh; al[rt][kd] = ll;
                }
            }
        }
    }
    __syncthreads();   // xt dead; B planes live

    // ---- K loop ----
    const int prow = tid >> 4;   // staging row residue
    const int pch  = tid & 15;   // staging chunk (8 shorts = 16B)
    int4 ph[8], pl[8];
    #pragma unroll
    for (int i = 0; i < 8; ++i) {
        int r = prow + i * 16;
        ph[i] = *(const int4*)(cbh + (size_t)r * Dc + pch * 8);
        pl[i] = *(const int4*)(cbl + (size_t)r * Dc + pch * 8);
    }
    float Bb[16], Ss[16]; int Kk[16];
    #pragma unroll
    for (int i = 0; i < 16; ++i) { Bb[i] = -3.0e38f; Ss[i] = -3.0e38f; Kk[i] = 0; }
    const int Cbase = (w & 1) * 64;

    for (int t = 0; t < 32; ++t) {
        __syncthreads();   // previous tile's readers done
        #pragma unroll
        for (int i = 0; i < 8; ++i) {
            int r = prow + i * 16;
            int pc = pch ^ (r & 15);             // XOR swizzle -> bank-uniform
            *(int4*)(bhp + r * 128 + pc * 8) = ph[i];
            *(int4*)(blp + r * 128 + pc * 8) = pl[i];
        }
        __syncthreads();
        if (t < 31) {   // prefetch next tile (hidden under MFMA)
            #pragma unroll
            for (int i = 0; i < 8; ++i) {
                int r = prow + i * 16;
                ph[i] = *(const int4*)(cbh + ((size_t)(t + 1) * 128 + r) * Dc + pch * 8);
                pl[i] = *(const int4*)(cbl + ((size_t)(t + 1) * 128 + r) * Dc + pch * 8);
            }
        }
        f32x4 acc[4][4];
        #pragma unroll
        for (int rt = 0; rt < 4; ++rt)
            #pragma unroll
            for (int ct = 0; ct < 4; ++ct) { f32x4 z = {0.f, 0.f, 0.f, 0.f}; acc[rt][ct] = z; }

        #pragma unroll
        for (int kd = 0; kd < 4; ++kd) {
            short8 bh[4], bl[4];
            #pragma unroll
            for (int ct = 0; ct < 4; ++ct) {
                int r = Cbase + ct * 16 + m16;   // B^T row = code
                int ch = kd * 4 + quad;
                int pc = ch ^ (r & 15);
                bh[ct] = *(const short8*)(bhp + r * 128 + pc * 8);
                bl[ct] = *(const short8*)(blp + r * 128 + pc * 8);
            }
            #pragma unroll
            for (int rt = 0; rt < 4; ++rt)
                #pragma unroll
                for (int ct = 0; ct < 4; ++ct) {
                    acc[rt][ct] = __builtin_amdgcn_mfma_f32_16x16x32_bf16(ah[rt][kd], bh[ct], acc[rt][ct], 0, 0, 0);
                    acc[rt][ct] = __builtin_amdgcn_mfma_f32_16x16x32_bf16(ah[rt][kd], bl[ct], acc[rt][ct], 0, 0, 0);
                    acc[rt][ct] = __builtin_amdgcn_mfma_f32_16x16x32_bf16(al[rt][kd], bh[ct], acc[rt][ct], 0, 0, 0);
                }
        }
        // fold 4 col-candidates per row slot into running (best, second, idx)
        #pragma unroll
        for (int rt = 0; rt < 4; ++rt)
            #pragma unroll
            for (int rg = 0; rg < 4; ++rg) {
                int s = rt * 4 + rg;
                float c0 = acc[rt][0][rg], c1 = acc[rt][1][rg];
                float c2 = acc[rt][2][rg], c3 = acc[rt][3][rg];
                float m01 = fmaxf(c0, c1), m23 = fmaxf(c2, c3);
                int  i01 = (c1 > c0) ? 1 : 0;
                int  i23 = (c3 > c2) ? 3 : 2;
                bool cm  = m23 > m01;           // strict: ties keep smaller code
                float mm = fmaxf(m01, m23);
                int  im  = cm ? i23 : i01;
                float nw = cm ? fminf(c2, c3) : fminf(c0, c1);
                float sec4 = fmaxf(fminf(m01, m23), nw);
                if (mm > Bb[s]) {
                    Ss[s] = fmaxf(fmaxf(Ss[s], Bb[s]), sec4);
                    Bb[s] = mm; Kk[s] = t * 4 + im;
                } else {
                    Ss[s] = fmaxf(Ss[s], mm);   // tie -> Ss==Bb -> margin 0 -> repair
                }
            }
    }

    // ---- epilogue: cross-contributor reduce (2 passes of 64 rows) ----
    if (tid == 0) *bsum = 0.f;
    #pragma unroll 1
    for (int p = 0; p < 2; ++p) {
        __syncthreads();
        if ((w >> 1) == p) {
            #pragma unroll
            for (int rt = 0; rt < 4; ++rt)
                #pragma unroll
                for (int rg = 0; rg < 4; ++rg) {
                    int row = rt * 16 + quad * 4 + rg;        // C layout row
                    int contrib = (w & 1) * 16 + m16;
                    int s = rt * 4 + rg;
                    Ev[row * 32 + contrib] = Bb[s];
                    Sv[row * 32 + contrib] = Ss[s];
                    int ck = Kk[s];
                    Kv[row * 32 + contrib] = (ck >> 2) * 128 + (ck & 3) * 16 + Cbase + m16;
                }
        }
        __syncthreads();
        {
            int row = tid >> 2, q = tid & 3;
            float v1 = -3.0e38f, v2 = -3.0e38f; int k1 = 0x7fffffff;
            #pragma unroll
            for (int j = 0; j < 8; ++j) {
                int ci = q * 8 + j;
                float Bi = Ev[row * 32 + ci];
                float Si = Sv[row * 32 + ci];
                int   Ki = Kv[row * 32 + ci];
                if (Bi > v1)      { v2 = fmaxf(fmaxf(v2, v1), Si); v1 = Bi; k1 = Ki; }
                else if (Bi == v1){ k1 = min(k1, Ki); v2 = fmaxf(v2, Bi); }
                else              { v2 = fmaxf(v2, Bi); }
            }
            #pragma unroll
            for (int off = 2; off >= 1; off >>= 1) {
                float ov1 = __shfl_down(v1, off);
                float ov2 = __shfl_down(v2, off);
                int   ok1 = __shfl_down(k1, off);
                if (ov1 > v1)      { v2 = fmaxf(fmaxf(v2, v1), ov2); v1 = ov1; k1 = ok1; }
                else if (ov1 == v1){ k1 = min(k1, ok1); v2 = fmaxf(v2, fmaxf(ov1, ov2)); }
                else               { v2 = fmaxf(v2, fmaxf(ov1, ov2)); }
            }
            if (q == 0) {
                int n = n0 + p * 64 + row;
                idx_out[n] = k1;
                atomicAdd(bsum, v1);
                if (v1 - v2 < TAU) {
                    int pos = atomicAdd(rcnt, 1);
                    if (pos < RCAP) rlist[pos] = n;
                }
            }
        }
    }
    __syncthreads();
    if (tid == 0) atomicAdd(lossacc, *bsum);
}

// ---------------------------------------------------------------------------
// Exact fp32 re-argmax for flagged (near-tie) queries.
// ---------------------------------------------------------------------------
__global__ void k_repair(const float* __restrict__ x, const float* __restrict__ invn,
                         const float* __restrict__ cbn, int* __restrict__ idx,
                         const int* __restrict__ rcnt, const int* __restrict__ rlist) {
    __shared__ float xs[128];
    __shared__ float rv[4]; __shared__ int rk[4];
    int cnt = *rcnt; if (cnt > RCAP) cnt = RCAP;
    for (int e = blockIdx.x; e < cnt; e += gridDim.x) {
        int n = rlist[e]; int b = n >> 12; int l = n & (Lc - 1);
        __syncthreads();
        if (threadIdx.x < 128)
            xs[threadIdx.x] = x[(size_t)b * Dc * Lc + (size_t)threadIdx.x * Lc + l] * invn[n];
        __syncthreads();
        const float4* xv = (const float4*)xs;
        float best = -3.0e38f; int bk = 0x7fffffff;
        for (int k = threadIdx.x; k < Kc; k += 256) {
            const float4* cr = (const float4*)(cbn + (size_t)k * Dc);
            float s = 0.f;
            #pragma unroll
            for (int j = 0; j < 32; ++j) {
                float4 c = cr[j], xx = xv[j];
                s += c.x * xx.x + c.y * xx.y + c.z * xx.z + c.w * xx.w;
            }
            if (s > best || (s == best && k < bk)) { best = s; bk = k; }
        }
        #pragma unroll
        for (int off = 32; off >= 1; off >>= 1) {
            float ov = __shfl_down(best, off); int ok = __shfl_down(bk, off);
            if (ov > best || (ov == best && ok < bk)) { best = ov; bk = ok; }
        }
        int wv = threadIdx.x >> 6;
        if ((threadIdx.x & 63) == 0) { rv[wv] = best; rk[wv] = bk; }
        __syncthreads();
        if (threadIdx.x == 0) {
            for (int i = 1; i < 4; ++i)
                if (rv[i] > best || (rv[i] == best && rk[i] < bk)) { best = rv[i]; bk = rk[i]; }
            idx[n] = bk;
        }
    }
}

// ---------------------------------------------------------------------------
// out[b][d][l] = cbn[idx[n]][d]
// ---------------------------------------------------------------------------
__global__ void k_gather(const float* __restrict__ cbn, const int* __restrict__ idx,
                         float* __restrict__ out) {
    __shared__ int sidx[64];
    int n0 = blockIdx.x << 6;
    int b  = n0 >> 12;
    int l0 = n0 & (Lc - 1);
    if (threadIdx.x < 64) sidx[threadIdx.x] = idx[n0 + threadIdx.x];
    __syncthreads();
    int t = threadIdx.x;
    #pragma unroll
    for (int i = 0; i < 32; ++i) {
        int p = t + (i << 8);
        int d = p >> 6;
        int l = p & 63;
        out[(size_t)b * Dc * Lc + (size_t)d * Lc + l0 + l] = cbn[(size_t)sidx[l] * Dc + d];
    }
}

__global__ void k_loss(const float* __restrict__ lacc, float* __restrict__ oloss) {
    *oloss = 2.0f - 2.0f * (*lacc) / (float)Nc;
}

// ---------------------------------------------------------------------------
extern "C" void kernel_launch(void* const* d_in, const int* in_sizes, int n_in,
                              void* d_out, int out_size, void* d_ws, size_t ws_size,
                              hipStream_t stream) {
    const float* x   = (const float*)d_in[0];   // [16][128][4096] fp32
    const float* emb = (const float*)d_in[1];   // [4096][128] fp32
    float* out = (float*)d_out;

    char* ws = (char*)d_ws;
    float*          cbn  = (float*)ws;                                  // 2 MB
    unsigned short* cbh  = (unsigned short*)(ws + (2u << 20));          // 1 MB
    unsigned short* cbl  = (unsigned short*)(ws + (3u << 20));          // 1 MB
    float*          invn = (float*)(ws + (4u << 20));                   // 256 KB
    int*            idx  = (int*)(ws + (4u << 20) + (256u << 10));      // 256 KB
    float*          lacc = (float*)(ws + (4u << 20) + (512u << 10));
    int*            rcnt = (int*)(ws + (4u << 20) + (512u << 10) + 64);
    int*            rlist= (int*)(ws + (4u << 20) + (512u << 10) + 128);// 32 KB

    k_cbprep<<<Kc / 4,   256, 0, stream>>>(emb, cbn, cbh, cbl, lacc, rcnt);
    k_argmax<<<Nc / 128, 256, 0, stream>>>(x, cbh, cbl, invn, idx, lacc, rcnt, rlist);
    k_repair<<<128,      256, 0, stream>>>(x, invn, cbn, idx, rcnt, rlist);
    k_gather<<<Nc / 64,  256, 0, stream>>>(cbn, idx, out);
    k_loss  <<<1, 1,     0, stream>>>(lacc, out + (size_t)Bc * Dc * Lc);
}

// Round 3
// 555.829 us; speedup vs baseline: 1.9461x; 1.9461x over previous
//
#include <hip/hip_runtime.h>
#include <cstddef>

#define EPSF 1e-12f

constexpr int Bc = 16, Dc = 128, Lc = 4096, Kc = 4096;
constexpr int Nc = Bc * Lc;   // 65536
constexpr float TAU = 2e-4f;  // repair margin (worst-case split err ~1e-5)
constexpr int RCAP = 32768;

typedef __attribute__((ext_vector_type(8))) short short8;
typedef __attribute__((ext_vector_type(4))) float f32x4;

__device__ __forceinline__ unsigned short f2bf(float f) {
    unsigned u = __float_as_uint(f);
    return (unsigned short)((u + 0x7fffu + ((u >> 16) & 1u)) >> 16);
}
__device__ __forceinline__ float bf2f(unsigned short u) {
    return __uint_as_float(((unsigned)u) << 16);
}

// ---------------------------------------------------------------------------
// Normalize codebook -> cbn (f32) + cbh/cbl (bf16 split). Init loss/rcnt.
// ---------------------------------------------------------------------------
__global__ void k_cbprep(const float* __restrict__ emb, float* __restrict__ cbn,
                         unsigned short* __restrict__ cbh, unsigned short* __restrict__ cbl,
                         float* __restrict__ lacc, int* __restrict__ rcnt) {
    int k    = (blockIdx.x << 2) + (threadIdx.x >> 6);
    int lane = threadIdx.x & 63;
    float2 v = ((const float2*)(emb + (size_t)k * Dc))[lane];
    float s = v.x * v.x + v.y * v.y;
    #pragma unroll
    for (int off = 32; off > 0; off >>= 1) s += __shfl_down(s, off);
    s = __shfl(s, 0);
    float inv = 1.f / fmaxf(sqrtf(s), EPSF);
    v.x *= inv; v.y *= inv;
    ((float2*)(cbn + (size_t)k * Dc))[lane] = v;
    unsigned short h0 = f2bf(v.x), h1 = f2bf(v.y);
    ((unsigned int*)(cbh + (size_t)k * Dc))[lane] = (unsigned)h0 | ((unsigned)h1 << 16);
    unsigned short l0b = f2bf(v.x - bf2f(h0)), l1b = f2bf(v.y - bf2f(h1));
    ((unsigned int*)(cbl + (size_t)k * Dc))[lane] = (unsigned)l0b | ((unsigned)l1b << 16);
    if (blockIdx.x == 0 && threadIdx.x == 0) { *lacc = 0.f; *rcnt = 0; }
}

// ---------------------------------------------------------------------------
// MFMA argmax, spill-free edition.
// Block = 256 thr / 4 waves, 128 rows. Wave w owns rows w*32..w*32+31:
//   A frags 2rt x 4kd x {hi,lo} = 64 VGPR, held for the whole kernel.
// B: 64-code tiles, double-buffered LDS (2 x 32KB), XOR-swizzled chunks,
// register prefetch = 8 int4 = 32 VGPR. One barrier per tile; the vmcnt
// wait for the prefetch lands before the ds_write with a full tile of MFMA
// as slack. acc = 8 f32x4 (AGPR). Epilogue = in-wave shfl_xor merge.
// ---------------------------------------------------------------------------
__global__ __launch_bounds__(256, 1)
void k_argmax(const float* __restrict__ x, const unsigned short* __restrict__ cbh,
              const unsigned short* __restrict__ cbl, float* __restrict__ invn,
              int* __restrict__ idx_out, float* __restrict__ lossacc,
              int* __restrict__ rcnt, int* __restrict__ rlist) {
    __shared__ __align__(16) char smem[65536];
    float* xt   = (float*)smem;              // [64][129] f32 (preamble)
    float* invl = (float*)(smem + 33024);    // [64]      (preamble)

    const int tid  = threadIdx.x;
    const int w    = tid >> 6;
    const int lane = tid & 63;
    const int m16  = lane & 15;
    const int quad = lane >> 4;
    const int n0   = blockIdx.x * 128;
    const int bI   = n0 >> 12;
    const int l0   = n0 & (Lc - 1);
    const float* xb = x + (size_t)bI * Dc * Lc;

    // ---- initial B-tile prefetch (in flight across the whole preamble) ----
    const int pr  = tid >> 4;        // code-row residue 0..15
    const int pch = tid & 15;        // 16B chunk 0..15
    const int pcw = pch ^ pr;        // swizzled write chunk (r&15 == pr)
    int4 ph[4], pl[4];
    #pragma unroll
    for (int i = 0; i < 4; ++i) {
        int r = pr + i * 16;
        ph[i] = ((const int4*)(cbh + (size_t)r * Dc))[pch];
        pl[i] = ((const int4*)(cbl + (size_t)r * Dc))[pch];
    }

    // ---- preamble: transpose+normalize x, build per-wave A fragments ----
    short8 ah[2][4], al[2][4];
    for (int h = 0; h < 2; ++h) {
        __syncthreads();
        #pragma unroll
        for (int j = 0; j < 8; ++j) {
            int fl = tid + j * 256;
            int d = fl >> 4, lq = fl & 15;
            float4 v = *(const float4*)(xb + (size_t)d * Lc + l0 + h * 64 + lq * 4);
            xt[(lq * 4 + 0) * 129 + d] = v.x;
            xt[(lq * 4 + 1) * 129 + d] = v.y;
            xt[(lq * 4 + 2) * 129 + d] = v.z;
            xt[(lq * 4 + 3) * 129 + d] = v.w;
        }
        __syncthreads();
        {   // row norms, 4 threads/row
            int row = tid >> 2, q = tid & 3;
            float s = 0.f;
            #pragma unroll
            for (int j = 0; j < 32; ++j) { float t = xt[row * 129 + q * 32 + j]; s += t * t; }
            s += __shfl_down(s, 1); s += __shfl_down(s, 2);
            if (q == 0) {
                float inv = 1.f / fmaxf(sqrtf(s), EPSF);
                invl[row] = inv;
                invn[n0 + h * 64 + row] = inv;
            }
        }
        __syncthreads();
        if ((w >> 1) == h) {   // waves 2h, 2h+1 own these 64 rows (32 each)
            #pragma unroll
            for (int rt = 0; rt < 2; ++rt) {
                int rl = (w & 1) * 32 + rt * 16 + m16;   // A layout: m = lane&15
                float inv = invl[rl];
                #pragma unroll
                for (int kd = 0; kd < 4; ++kd) {
                    int dof = kd * 32 + quad * 8;        // k = quad*8+j
                    short8 hh, ll;
                    #pragma unroll
                    for (int j = 0; j < 8; ++j) {
                        float xn = xt[rl * 129 + dof + j] * inv;
                        unsigned short hb = f2bf(xn);
                        hh[j] = (short)hb;
                        ll[j] = (short)f2bf(xn - bf2f(hb));
                    }
                    ah[rt][kd] = hh; al[rt][kd] = ll;
                }
            }
        }
    }
    __syncthreads();   // xt dead; B double-buffer takes over the LDS

    // ---- K loop: 64 tiles of 64 codes ----
    float Bb[8], Ss[8]; int Kk[8];
    #pragma unroll
    for (int i = 0; i < 8; ++i) { Bb[i] = -3.0e38f; Ss[i] = -3.0e38f; Kk[i] = 0; }

    for (int t = 0; t < 64; ++t) {
        char* base = smem + (t & 1) * 32768;
        unsigned short* bh_p = (unsigned short*)base;
        unsigned short* bl_p = (unsigned short*)(base + 16384);
        // stage prefetched tile (vmcnt wait lands here, a full tile after issue)
        #pragma unroll
        for (int i = 0; i < 4; ++i) {
            int r = pr + i * 16;
            ((int4*)(bh_p + r * 128))[pcw] = ph[i];
            ((int4*)(bl_p + r * 128))[pcw] = pl[i];
        }
        __syncthreads();
        if (t < 63) {   // issue next tile's loads; consumed next iteration
            #pragma unroll
            for (int i = 0; i < 4; ++i) {
                size_t r = (size_t)(t + 1) * 64 + pr + i * 16;
                ph[i] = ((const int4*)(cbh + r * Dc))[pch];
                pl[i] = ((const int4*)(cbl + r * Dc))[pch];
            }
        }

        f32x4 acc[2][4];
        #pragma unroll
        for (int rt = 0; rt < 2; ++rt)
            #pragma unroll
            for (int ct = 0; ct < 4; ++ct) { f32x4 z = {0.f, 0.f, 0.f, 0.f}; acc[rt][ct] = z; }

        #pragma unroll
        for (int kd = 0; kd < 4; ++kd) {
            short8 bh[4], bl[4];
            #pragma unroll
            for (int ct = 0; ct < 4; ++ct) {
                int r2 = ct * 16 + m16;              // code within tile
                int pc = (kd * 4 + quad) ^ m16;      // swizzled chunk
                bh[ct] = *(const short8*)(bh_p + r2 * 128 + pc * 8);
                bl[ct] = *(const short8*)(bl_p + r2 * 128 + pc * 8);
            }
            // pass-major order: same-acc dependency distance = 8 MFMAs
            #pragma unroll
            for (int rt = 0; rt < 2; ++rt)
                #pragma unroll
                for (int ct = 0; ct < 4; ++ct)
                    acc[rt][ct] = __builtin_amdgcn_mfma_f32_16x16x32_bf16(ah[rt][kd], bh[ct], acc[rt][ct], 0, 0, 0);
            #pragma unroll
            for (int rt = 0; rt < 2; ++rt)
                #pragma unroll
                for (int ct = 0; ct < 4; ++ct)
                    acc[rt][ct] = __builtin_amdgcn_mfma_f32_16x16x32_bf16(ah[rt][kd], bl[ct], acc[rt][ct], 0, 0, 0);
            #pragma unroll
            for (int rt = 0; rt < 2; ++rt)
                #pragma unroll
                for (int ct = 0; ct < 4; ++ct)
                    acc[rt][ct] = __builtin_amdgcn_mfma_f32_16x16x32_bf16(al[rt][kd], bh[ct], acc[rt][ct], 0, 0, 0);
        }

        // fold 4 col-candidates per row-slot into running (best, second, idx)
        #pragma unroll
        for (int rt = 0; rt < 2; ++rt)
            #pragma unroll
            for (int rg = 0; rg < 4; ++rg) {
                int s = rt * 4 + rg;
                float c0 = acc[rt][0][rg], c1 = acc[rt][1][rg];
                float c2 = acc[rt][2][rg], c3 = acc[rt][3][rg];
                float m01 = fmaxf(c0, c1), m23 = fmaxf(c2, c3);
                int  i01 = (c1 > c0) ? 1 : 0;
                int  i23 = (c3 > c2) ? 3 : 2;
                bool cm  = m23 > m01;               // ties keep smaller code
                float mm = fmaxf(m01, m23);
                int  im  = cm ? i23 : i01;
                float nw = cm ? fminf(c2, c3) : fminf(c0, c1);
                float sec4 = fmaxf(fminf(m01, m23), nw);
                if (mm > Bb[s]) {
                    Ss[s] = fmaxf(fmaxf(Ss[s], Bb[s]), sec4);
                    Bb[s] = mm; Kk[s] = t * 4 + im;
                } else {
                    Ss[s] = fmaxf(Ss[s], mm);
                }
            }
    }

    // ---- epilogue: in-wave merge over the 16 col-contributors ----
    float lossl = 0.f;
    #pragma unroll
    for (int s = 0; s < 8; ++s) {
        int rt = s >> 2, rg = s & 3;
        float v1 = Bb[s], v2 = Ss[s];
        int k1 = (Kk[s] >> 2) * 64 + (Kk[s] & 3) * 16 + m16;  // global code
        #pragma unroll
        for (int off = 1; off < 16; off <<= 1) {
            float ov1 = __shfl_xor(v1, off);
            float ov2 = __shfl_xor(v2, off);
            int   ok1 = __shfl_xor(k1, off);
            if (ov1 > v1)       { v2 = fmaxf(fmaxf(v2, v1), ov2); v1 = ov1; k1 = ok1; }
            else if (ov1 == v1) { k1 = min(k1, ok1); v2 = fmaxf(v2, fmaxf(ov1, ov2)); }
            else                { v2 = fmaxf(v2, fmaxf(ov1, ov2)); }
        }
        if (m16 == 0) {
            int n = n0 + w * 32 + rt * 16 + quad * 4 + rg;   // C row = quad*4+reg
            idx_out[n] = k1;
            lossl += v1;
            if (v1 - v2 < TAU) {
                int pos = atomicAdd(rcnt, 1);
                if (pos < RCAP) rlist[pos] = n;
            }
        }
    }
    float p = (m16 == 0) ? lossl : 0.f;
    p += __shfl_xor(p, 16);
    p += __shfl_xor(p, 32);
    if (lane == 0) atomicAdd(lossacc, p);
}

// ---------------------------------------------------------------------------
// Exact fp32 re-argmax for flagged queries. 512 blocks, grid-stride.
// ---------------------------------------------------------------------------
__global__ void k_repair(const float* __restrict__ x, const float* __restrict__ invn,
                         const float* __restrict__ cbn, int* __restrict__ idx,
                         const int* __restrict__ rcnt, const int* __restrict__ rlist) {
    __shared__ float xs[128];
    __shared__ float rv[4]; __shared__ int rk[4];
    int cnt = *rcnt; if (cnt > RCAP) cnt = RCAP;
    for (int e = blockIdx.x; e < cnt; e += gridDim.x) {
        int n = rlist[e]; int b = n >> 12; int l = n & (Lc - 1);
        __syncthreads();
        if (threadIdx.x < 128)
            xs[threadIdx.x] = x[(size_t)b * Dc * Lc + (size_t)threadIdx.x * Lc + l] * invn[n];
        __syncthreads();
        const float4* xv = (const float4*)xs;
        float best = -3.0e38f; int bk = 0x7fffffff;
        for (int k = threadIdx.x; k < Kc; k += 256) {
            const float4* cr = (const float4*)(cbn + (size_t)k * Dc);
            float s = 0.f;
            #pragma unroll
            for (int j = 0; j < 32; ++j) {
                float4 c = cr[j], xx = xv[j];
                s += c.x * xx.x + c.y * xx.y + c.z * xx.z + c.w * xx.w;
            }
            if (s > best || (s == best && k < bk)) { best = s; bk = k; }
        }
        #pragma unroll
        for (int off = 32; off >= 1; off >>= 1) {
            float ov = __shfl_down(best, off); int ok = __shfl_down(bk, off);
            if (ov > best || (ov == best && ok < bk)) { best = ov; bk = ok; }
        }
        int wv = threadIdx.x >> 6;
        if ((threadIdx.x & 63) == 0) { rv[wv] = best; rk[wv] = bk; }
        __syncthreads();
        if (threadIdx.x == 0) {
            for (int i = 1; i < 4; ++i)
                if (rv[i] > best || (rv[i] == best && rk[i] < bk)) { best = rv[i]; bk = rk[i]; }
            idx[n] = bk;
        }
    }
}

// ---------------------------------------------------------------------------
__global__ void k_gather(const float* __restrict__ cbn, const int* __restrict__ idx,
                         float* __restrict__ out) {
    __shared__ int sidx[64];
    int n0 = blockIdx.x << 6;
    int b  = n0 >> 12;
    int l0 = n0 & (Lc - 1);
    if (threadIdx.x < 64) sidx[threadIdx.x] = idx[n0 + threadIdx.x];
    __syncthreads();
    int t = threadIdx.x;
    #pragma unroll
    for (int i = 0; i < 32; ++i) {
        int p = t + (i << 8);
        int d = p >> 6;
        int l = p & 63;
        out[(size_t)b * Dc * Lc + (size_t)d * Lc + l0 + l] = cbn[(size_t)sidx[l] * Dc + d];
    }
}

__global__ void k_loss(const float* __restrict__ lacc, float* __restrict__ oloss) {
    *oloss = 2.0f - 2.0f * (*lacc) / (float)Nc;
}

// ---------------------------------------------------------------------------
extern "C" void kernel_launch(void* const* d_in, const int* in_sizes, int n_in,
                              void* d_out, int out_size, void* d_ws, size_t ws_size,
                              hipStream_t stream) {
    const float* x   = (const float*)d_in[0];   // [16][128][4096] fp32
    const float* emb = (const float*)d_in[1];   // [4096][128] fp32
    float* out = (float*)d_out;

    char* ws = (char*)d_ws;
    float*          cbn  = (float*)ws;                                   // 2 MB
    unsigned short* cbh  = (unsigned short*)(ws + (2u << 20));           // 1 MB
    unsigned short* cbl  = (unsigned short*)(ws + (3u << 20));           // 1 MB
    float*          invn = (float*)(ws + (4u << 20));                    // 256 KB
    int*            idx  = (int*)(ws + (4u << 20) + (256u << 10));       // 256 KB
    float*          lacc = (float*)(ws + (4u << 20) + (512u << 10));
    int*            rcnt = (int*)(ws + (4u << 20) + (512u << 10) + 64);
    int*            rlist= (int*)(ws + (4u << 20) + (512u << 10) + 128); // 128 KB

    k_cbprep<<<Kc / 4,   256, 0, stream>>>(emb, cbn, cbh, cbl, lacc, rcnt);
    k_argmax<<<Nc / 128, 256, 0, stream>>>(x, cbh, cbl, invn, idx, lacc, rcnt, rlist);
    k_repair<<<512,      256, 0, stream>>>(x, invn, cbn, idx, rcnt, rlist);
    k_gather<<<Nc / 64,  256, 0, stream>>>(cbn, idx, out);
    k_loss  <<<1, 1,     0, stream>>>(lacc, out + (size_t)Bc * Dc * Lc);
}